// Round 1
// baseline (517.900 us; speedup 1.0000x reference)
//
#include <hip/hip_runtime.h>
#include <stdint.h>

typedef __bf16 bf16_t;
typedef bf16_t bf16x8 __attribute__((ext_vector_type(8)));
typedef bf16_t bf16x4 __attribute__((ext_vector_type(4)));
typedef float  f32x4  __attribute__((ext_vector_type(4)));

#define IN_C 512
#define HID  256
#define OUTC 128

// ---------------- edge format detection / decode ----------------
__global__ void k_detect(const void* __restrict__ ei, int* __restrict__ flag, int n_nodes) {
  if (blockIdx.x == 0 && threadIdx.x == 0) {
    const long long* p = (const long long*)ei;
    int ok = 1;
    for (int i = 0; i < 64; ++i) {
      long long v = p[i];
      if (v < 0 || v >= n_nodes) ok = 0;
    }
    *flag = ok;  // 1 => int64 layout, 0 => int32 layout
  }
}

__global__ void k_decode(const void* __restrict__ ei, const int* __restrict__ flag,
                         int* __restrict__ srcI, int* __restrict__ dstI, int E) {
  int e = blockIdx.x * blockDim.x + threadIdx.x;
  if (e >= E) return;
  if (*flag) {
    const long long* p = (const long long*)ei;
    srcI[e] = (int)p[e];
    dstI[e] = (int)p[(size_t)E + e];
  } else {
    const int* p = (const int*)ei;
    srcI[e] = p[e];
    dstI[e] = p[E + e];
  }
}

// ---------------- degree / dinv ----------------
__global__ void k_hist(const int* __restrict__ dstI, int* __restrict__ cnt, int E) {
  int e = blockIdx.x * blockDim.x + threadIdx.x;
  if (e < E) atomicAdd(&cnt[dstI[e]], 1);
}

__global__ void k_dinv(const int* __restrict__ cnt, float* __restrict__ dinv, int n) {
  int i = blockIdx.x * blockDim.x + threadIdx.x;
  if (i < n) dinv[i] = rsqrtf((float)cnt[i] + 1.0f);  // +1 self-loop
}

// ---------------- CSR build: exclusive scan (3 kernels) + fill ----------------
__global__ void k_scan1(const int* __restrict__ cnt, int* __restrict__ ex,
                        int* __restrict__ part, int n) {
  __shared__ int sh[256];
  int i = blockIdx.x * 256 + threadIdx.x;
  int v = (i < n) ? cnt[i] : 0;
  sh[threadIdx.x] = v;
  __syncthreads();
  int val = v;
  for (int off = 1; off < 256; off <<= 1) {
    int t = (threadIdx.x >= off) ? sh[threadIdx.x - off] : 0;
    __syncthreads();
    val += t;
    sh[threadIdx.x] = val;
    __syncthreads();
  }
  if (i < n) ex[i] = val - v;         // exclusive within block
  if (threadIdx.x == 255) part[blockIdx.x] = val;  // block total
}

__global__ void k_scan2(int* __restrict__ part, int nb) {
  __shared__ int sh[256];
  int v = (threadIdx.x < nb) ? part[threadIdx.x] : 0;
  sh[threadIdx.x] = v;
  __syncthreads();
  int val = v;
  for (int off = 1; off < 256; off <<= 1) {
    int t = (threadIdx.x >= off) ? sh[threadIdx.x - off] : 0;
    __syncthreads();
    val += t;
    sh[threadIdx.x] = val;
    __syncthreads();
  }
  if (threadIdx.x < nb) part[threadIdx.x] = val - v;  // exclusive block offsets
}

__global__ void k_scan3(int* __restrict__ rs, const int* __restrict__ part,
                        int* __restrict__ cur, int n, int Etot) {
  int i = blockIdx.x * 256 + threadIdx.x;
  if (i < n) {
    int r = rs[i] + part[blockIdx.x];
    rs[i] = r;
    cur[i] = r;
  }
  if (i == 0) rs[n] = Etot;
}

__global__ void k_fill(const int* __restrict__ srcI, const int* __restrict__ dstI,
                       int* __restrict__ cur, int* __restrict__ csr, int E) {
  int e = blockIdx.x * blockDim.x + threadIdx.x;
  if (e >= E) return;
  int p = atomicAdd(&cur[dstI[e]], 1);
  csr[p] = srcI[e];
}

// ---------------- conversions ----------------
// x [n,512] fp32 -> Xb [mpad,512] bf16 (pad rows zero)
__global__ void k_convx(const float* __restrict__ x, bf16_t* __restrict__ Xb,
                        int n, int mpad) {
  int t = blockIdx.x * blockDim.x + threadIdx.x;  // mpad*64 tasks, 8 elems each
  int r = t >> 6, c8 = t & 63;
  if (r >= mpad) return;
  bf16x8 o;
  if (r < n) {
    const float4* px = (const float4*)(x + (size_t)r * IN_C);
    float4 a = px[c8 * 2];
    float4 b = px[c8 * 2 + 1];
    o[0] = (bf16_t)a.x; o[1] = (bf16_t)a.y; o[2] = (bf16_t)a.z; o[3] = (bf16_t)a.w;
    o[4] = (bf16_t)b.x; o[5] = (bf16_t)b.y; o[6] = (bf16_t)b.z; o[7] = (bf16_t)b.w;
  } else {
    for (int i = 0; i < 8; ++i) o[i] = (bf16_t)0.0f;
  }
  *(bf16x8*)(Xb + (size_t)r * IN_C + c8 * 8) = o;
}

// W [K,N] fp32 -> Wt [N,K] bf16
__global__ void k_transpose(const float* __restrict__ W, bf16_t* __restrict__ Wt,
                            int K, int Ncols) {
  int t = blockIdx.x * blockDim.x + threadIdx.x;
  if (t >= K * Ncols) return;
  int k = t / Ncols, nn = t % Ncols;
  Wt[(size_t)nn * K + k] = (bf16_t)W[t];
}

// ---------------- bf16 MFMA GEMM: C[M,N] = A[M,K] * Bt[N,K]^T ----------------
// BM=BN=128, BK=32, 256 threads (4 waves, 2x2 of 64x64), 16x16x32 MFMA.
__global__ __launch_bounds__(256, 2) void k_gemm(const bf16_t* __restrict__ A,
                                                 const bf16_t* __restrict__ Bt,
                                                 float* __restrict__ C,
                                                 int Kdim, int Ncols) {
  __shared__ bf16_t As[128 * 40];  // +8 pad to break bank-stride
  __shared__ bf16_t Bs[128 * 40];
  const int bm = blockIdx.x, bn = blockIdx.y;
  const int tid = threadIdx.x;
  const int wave = tid >> 6, lane = tid & 63;
  const int wm = (wave >> 1) * 64, wn = (wave & 1) * 64;
  const int quad = lane >> 4, l16 = lane & 15;
  const int seg = tid & 3;

  f32x4 acc[4][4];
  for (int i = 0; i < 4; ++i)
    for (int j = 0; j < 4; ++j)
      for (int r = 0; r < 4; ++r) acc[i][j][r] = 0.0f;

  for (int kk = 0; kk < Kdim; kk += 32) {
#pragma unroll
    for (int s = 0; s < 2; ++s) {
      int row = s * 64 + (tid >> 2);
      bf16x8 va = *(const bf16x8*)(A + (size_t)(bm * 128 + row) * Kdim + kk + seg * 8);
      *(bf16x8*)(&As[row * 40 + seg * 8]) = va;
      bf16x8 vb = *(const bf16x8*)(Bt + (size_t)(bn * 128 + row) * Kdim + kk + seg * 8);
      *(bf16x8*)(&Bs[row * 40 + seg * 8]) = vb;
    }
    __syncthreads();
    bf16x8 af[4], bfr[4];
#pragma unroll
    for (int i = 0; i < 4; ++i)
      af[i] = *(const bf16x8*)(&As[(wm + i * 16 + l16) * 40 + quad * 8]);
#pragma unroll
    for (int j = 0; j < 4; ++j)
      bfr[j] = *(const bf16x8*)(&Bs[(wn + j * 16 + l16) * 40 + quad * 8]);
#pragma unroll
    for (int i = 0; i < 4; ++i)
#pragma unroll
      for (int j = 0; j < 4; ++j)
        acc[i][j] = __builtin_amdgcn_mfma_f32_16x16x32_bf16(af[i], bfr[j], acc[i][j], 0, 0, 0);
    __syncthreads();
  }

#pragma unroll
  for (int i = 0; i < 4; ++i) {
#pragma unroll
    for (int j = 0; j < 4; ++j) {
      int col = bn * 128 + wn + j * 16 + l16;
      int row0 = bm * 128 + wm + i * 16 + quad * 4;
#pragma unroll
      for (int r = 0; r < 4; ++r)
        C[(size_t)(row0 + r) * Ncols + col] = acc[i][j][r];
    }
  }
}

// ---------------- layer-1 aggregation, fused bias+relu+bf16 (one wave / dst row) --
// R1b[d] = (d<n) ? bf16(relu(dinv[d]*sum_s dinv[s]*H1[s] + dinv[d]^2*H1[d] + b1)) : 0
__global__ void k_agg_l1(const float* __restrict__ H, const int* __restrict__ rs,
                         const int* __restrict__ csr, const float* __restrict__ dinv,
                         const float* __restrict__ b1, bf16_t* __restrict__ R,
                         int n, int mpad) {
  int d = blockIdx.x * 4 + (threadIdx.x >> 6);
  if (d >= mpad) return;
  int lane = threadIdx.x & 63;
  if (d >= n) {  // zero-pad rows for GEMM2
    bf16x4 z;
    z[0] = (bf16_t)0.0f; z[1] = (bf16_t)0.0f; z[2] = (bf16_t)0.0f; z[3] = (bf16_t)0.0f;
    *(bf16x4*)(R + (size_t)d * HID + lane * 4) = z;
    return;
  }
  int e0 = rs[d], e1 = rs[d + 1];
  float ax = 0.f, ay = 0.f, az = 0.f, aw = 0.f;
  for (int e = e0; e < e1; ++e) {
    int s = csr[e];
    float w = dinv[s];
    float4 h = ((const float4*)(H + (size_t)s * HID))[lane];
    ax += w * h.x; ay += w * h.y; az += w * h.z; aw += w * h.w;
  }
  float dd = dinv[d];
  float dv2 = dd * dd;
  float4 hs = ((const float4*)(H + (size_t)d * HID))[lane];
  float4 bb = ((const float4*)b1)[lane];
  float vx = fmaxf(ax * dd + dv2 * hs.x + bb.x, 0.f);
  float vy = fmaxf(ay * dd + dv2 * hs.y + bb.y, 0.f);
  float vz = fmaxf(az * dd + dv2 * hs.z + bb.z, 0.f);
  float vw = fmaxf(aw * dd + dv2 * hs.w + bb.w, 0.f);
  bf16x4 o;
  o[0] = (bf16_t)vx; o[1] = (bf16_t)vy; o[2] = (bf16_t)vz; o[3] = (bf16_t)vw;
  *(bf16x4*)(R + (size_t)d * HID + lane * 4) = o;
}

// ---------------- layer-2 aggregation, fused bias, writes d_out ----------------
__global__ void k_agg_l2(const float* __restrict__ H, const int* __restrict__ rs,
                         const int* __restrict__ csr, const float* __restrict__ dinv,
                         const float* __restrict__ b2, float* __restrict__ out, int n) {
  int d = blockIdx.x * 4 + (threadIdx.x >> 6);
  if (d >= n) return;
  int lane = threadIdx.x & 63;
  int e0 = rs[d], e1 = rs[d + 1];
  float ax = 0.f, ay = 0.f;
  for (int e = e0; e < e1; ++e) {
    int s = csr[e];
    float w = dinv[s];
    float2 h = ((const float2*)(H + (size_t)s * OUTC))[lane];
    ax += w * h.x; ay += w * h.y;
  }
  float dd = dinv[d];
  float dv2 = dd * dd;
  float2 hs = ((const float2*)(H + (size_t)d * OUTC))[lane];
  float2 bb = ((const float2*)b2)[lane];
  float2 o;
  o.x = ax * dd + dv2 * hs.x + bb.x;
  o.y = ay * dd + dv2 * hs.y + bb.y;
  ((float2*)(out + (size_t)d * OUTC))[lane] = o;
}

// ---------------- launch ----------------
extern "C" void kernel_launch(void* const* d_in, const int* in_sizes, int n_in,
                              void* d_out, int out_size, void* d_ws, size_t ws_size,
                              hipStream_t stream) {
  const float* x  = (const float*)d_in[0];
  const void*  ei = d_in[1];
  const float* W1 = (const float*)d_in[2];
  const float* b1 = (const float*)d_in[3];
  const float* W2 = (const float*)d_in[4];
  const float* b2 = (const float*)d_in[5];

  const int n = in_sizes[0] / IN_C;   // 50000
  const int E = in_sizes[1] / 2;      // 800000
  const int mpad = (n + 127) & ~127;  // 50048

  char* w = (char*)d_ws;
  size_t off = 0;
  auto alloc = [&](size_t bytes) -> void* {
    void* p = w + off;
    off = (off + bytes + 255) & ~(size_t)255;
    return p;
  };

  int*    flag = (int*)alloc(4);
  int*    srcI = (int*)alloc((size_t)E * 4);
  int*    dstI = (int*)alloc((size_t)E * 4);
  int*    cnt  = (int*)alloc((size_t)n * 4);
  float*  dinv = (float*)alloc((size_t)n * 4);
  int*    rs   = (int*)alloc((size_t)(n + 1) * 4);
  int*    cur  = (int*)alloc((size_t)n * 4);
  int*    part = (int*)alloc(1024);
  int*    csr  = (int*)alloc((size_t)E * 4);
  bf16_t* Xb   = (bf16_t*)alloc((size_t)mpad * IN_C * 2);
  bf16_t* W1t  = (bf16_t*)alloc((size_t)HID * IN_C * 2);
  float*  H1   = (float*)alloc((size_t)mpad * HID * 4);
  bf16_t* R1b  = (bf16_t*)alloc((size_t)mpad * HID * 2);
  bf16_t* W2t  = (bf16_t*)alloc((size_t)OUTC * HID * 2);
  float*  H2   = (float*)alloc((size_t)mpad * OUTC * 4);
  (void)ws_size; (void)n_in; (void)out_size;

  const int nb = (n + 255) / 256;

  hipMemsetAsync(cnt, 0, (size_t)n * 4, stream);
  k_detect<<<1, 64, 0, stream>>>(ei, flag, n);
  k_decode<<<(E + 255) / 256, 256, 0, stream>>>(ei, flag, srcI, dstI, E);
  k_hist<<<(E + 255) / 256, 256, 0, stream>>>(dstI, cnt, E);
  k_dinv<<<nb, 256, 0, stream>>>(cnt, dinv, n);
  k_scan1<<<nb, 256, 0, stream>>>(cnt, rs, part, n);
  k_scan2<<<1, 256, 0, stream>>>(part, nb);
  k_scan3<<<nb, 256, 0, stream>>>(rs, part, cur, n, E);
  k_fill<<<(E + 255) / 256, 256, 0, stream>>>(srcI, dstI, cur, csr, E);

  k_convx<<<(mpad * 64 + 255) / 256, 256, 0, stream>>>(x, Xb, n, mpad);
  k_transpose<<<(IN_C * HID + 255) / 256, 256, 0, stream>>>(W1, W1t, IN_C, HID);
  k_transpose<<<(HID * OUTC + 255) / 256, 256, 0, stream>>>(W2, W2t, HID, OUTC);

  k_gemm<<<dim3(mpad / 128, HID / 128), 256, 0, stream>>>(Xb, W1t, H1, IN_C, HID);
  k_agg_l1<<<(mpad + 3) / 4, 256, 0, stream>>>(H1, rs, csr, dinv, b1, R1b, n, mpad);
  k_gemm<<<dim3(mpad / 128, OUTC / 128), 256, 0, stream>>>(R1b, W2t, H2, HID, OUTC);
  k_agg_l2<<<(n + 3) / 4, 256, 0, stream>>>(H2, rs, csr, dinv, b2, (float*)d_out, n);
}

// Round 2
// 421.737 us; speedup vs baseline: 1.2280x; 1.2280x over previous
//
#include <hip/hip_runtime.h>
#include <stdint.h>

typedef __bf16 bf16_t;
typedef bf16_t bf16x8 __attribute__((ext_vector_type(8)));
typedef bf16_t bf16x4 __attribute__((ext_vector_type(4)));
typedef bf16_t bf16x2 __attribute__((ext_vector_type(2)));
typedef float  f32x4  __attribute__((ext_vector_type(4)));

#define IN_C 512
#define HID  256
#define OUTC 128

// ---------------- edge format detection ----------------
__global__ void k_detect(const void* __restrict__ ei, int* __restrict__ flag, int n_nodes) {
  if (blockIdx.x == 0 && threadIdx.x == 0) {
    const long long* p = (const long long*)ei;
    int ok = 1;
    for (int i = 0; i < 64; ++i) {
      long long v = p[i];
      if (v < 0 || v >= n_nodes) ok = 0;
    }
    *flag = ok;  // 1 => int64 layout, 0 => int32 layout
  }
}

// decode + degree histogram fused
__global__ void k_decode_hist(const void* __restrict__ ei, const int* __restrict__ flag,
                              int* __restrict__ srcI, int* __restrict__ dstI,
                              int* __restrict__ cnt, int E) {
  int e = blockIdx.x * blockDim.x + threadIdx.x;
  if (e >= E) return;
  int s, d;
  if (*flag) {
    const long long* p = (const long long*)ei;
    s = (int)p[e];
    d = (int)p[(size_t)E + e];
  } else {
    const int* p = (const int*)ei;
    s = p[e];
    d = p[E + e];
  }
  srcI[e] = s;
  dstI[e] = d;
  atomicAdd(&cnt[d], 1);
}

__global__ void k_dinv(const int* __restrict__ cnt, float* __restrict__ dinv, int n) {
  int i = blockIdx.x * blockDim.x + threadIdx.x;
  if (i < n) dinv[i] = rsqrtf((float)cnt[i] + 1.0f);  // +1 self-loop
}

// ---------------- CSR build: exclusive scan (3 kernels) + fill ----------------
__global__ void k_scan1(const int* __restrict__ cnt, int* __restrict__ ex,
                        int* __restrict__ part, int n) {
  __shared__ int sh[256];
  int i = blockIdx.x * 256 + threadIdx.x;
  int v = (i < n) ? cnt[i] : 0;
  sh[threadIdx.x] = v;
  __syncthreads();
  int val = v;
  for (int off = 1; off < 256; off <<= 1) {
    int t = (threadIdx.x >= off) ? sh[threadIdx.x - off] : 0;
    __syncthreads();
    val += t;
    sh[threadIdx.x] = val;
    __syncthreads();
  }
  if (i < n) ex[i] = val - v;
  if (threadIdx.x == 255) part[blockIdx.x] = val;
}

__global__ void k_scan2(int* __restrict__ part, int nb) {
  __shared__ int sh[256];
  int v = (threadIdx.x < nb) ? part[threadIdx.x] : 0;
  sh[threadIdx.x] = v;
  __syncthreads();
  int val = v;
  for (int off = 1; off < 256; off <<= 1) {
    int t = (threadIdx.x >= off) ? sh[threadIdx.x - off] : 0;
    __syncthreads();
    val += t;
    sh[threadIdx.x] = val;
    __syncthreads();
  }
  if (threadIdx.x < nb) part[threadIdx.x] = val - v;
}

__global__ void k_scan3(int* __restrict__ rs, const int* __restrict__ part,
                        int* __restrict__ cur, int n, int Etot) {
  int i = blockIdx.x * 256 + threadIdx.x;
  if (i < n) {
    int r = rs[i] + part[blockIdx.x];
    rs[i] = r;
    cur[i] = r;
  }
  if (i == 0) rs[n] = Etot;
}

__global__ void k_fill(const int* __restrict__ srcI, const int* __restrict__ dstI,
                       int* __restrict__ cur, int* __restrict__ csr, int E) {
  int e = blockIdx.x * blockDim.x + threadIdx.x;
  if (e >= E) return;
  int p = atomicAdd(&cur[dstI[e]], 1);
  csr[p] = srcI[e];
}

// ---------------- conversions ----------------
__global__ void k_convx(const float* __restrict__ x, bf16_t* __restrict__ Xb,
                        int n, int mpad) {
  int t = blockIdx.x * blockDim.x + threadIdx.x;
  int r = t >> 6, c8 = t & 63;
  if (r >= mpad) return;
  bf16x8 o;
  if (r < n) {
    const float4* px = (const float4*)(x + (size_t)r * IN_C);
    float4 a = px[c8 * 2];
    float4 b = px[c8 * 2 + 1];
    o[0] = (bf16_t)a.x; o[1] = (bf16_t)a.y; o[2] = (bf16_t)a.z; o[3] = (bf16_t)a.w;
    o[4] = (bf16_t)b.x; o[5] = (bf16_t)b.y; o[6] = (bf16_t)b.z; o[7] = (bf16_t)b.w;
  } else {
    for (int i = 0; i < 8; ++i) o[i] = (bf16_t)0.0f;
  }
  *(bf16x8*)(Xb + (size_t)r * IN_C + c8 * 8) = o;
}

__global__ void k_transpose(const float* __restrict__ W, bf16_t* __restrict__ Wt,
                            int K, int Ncols) {
  int t = blockIdx.x * blockDim.x + threadIdx.x;
  if (t >= K * Ncols) return;
  int k = t / Ncols, nn = t % Ncols;
  Wt[(size_t)nn * K + k] = (bf16_t)W[t];
}

// ---------------- bf16 MFMA GEMM: C[M,N] = A[M,K] * Bt[N,K]^T, bf16 output ----
__global__ __launch_bounds__(256, 2) void k_gemm(const bf16_t* __restrict__ A,
                                                 const bf16_t* __restrict__ Bt,
                                                 bf16_t* __restrict__ C,
                                                 int Kdim, int Ncols) {
  __shared__ bf16_t As[128 * 40];
  __shared__ bf16_t Bs[128 * 40];
  const int bm = blockIdx.x, bn = blockIdx.y;
  const int tid = threadIdx.x;
  const int wave = tid >> 6, lane = tid & 63;
  const int wm = (wave >> 1) * 64, wn = (wave & 1) * 64;
  const int quad = lane >> 4, l16 = lane & 15;
  const int seg = tid & 3;

  f32x4 acc[4][4];
  for (int i = 0; i < 4; ++i)
    for (int j = 0; j < 4; ++j)
      for (int r = 0; r < 4; ++r) acc[i][j][r] = 0.0f;

  for (int kk = 0; kk < Kdim; kk += 32) {
#pragma unroll
    for (int s = 0; s < 2; ++s) {
      int row = s * 64 + (tid >> 2);
      bf16x8 va = *(const bf16x8*)(A + (size_t)(bm * 128 + row) * Kdim + kk + seg * 8);
      *(bf16x8*)(&As[row * 40 + seg * 8]) = va;
      bf16x8 vb = *(const bf16x8*)(Bt + (size_t)(bn * 128 + row) * Kdim + kk + seg * 8);
      *(bf16x8*)(&Bs[row * 40 + seg * 8]) = vb;
    }
    __syncthreads();
    bf16x8 af[4], bfr[4];
#pragma unroll
    for (int i = 0; i < 4; ++i)
      af[i] = *(const bf16x8*)(&As[(wm + i * 16 + l16) * 40 + quad * 8]);
#pragma unroll
    for (int j = 0; j < 4; ++j)
      bfr[j] = *(const bf16x8*)(&Bs[(wn + j * 16 + l16) * 40 + quad * 8]);
#pragma unroll
    for (int i = 0; i < 4; ++i)
#pragma unroll
      for (int j = 0; j < 4; ++j)
        acc[i][j] = __builtin_amdgcn_mfma_f32_16x16x32_bf16(af[i], bfr[j], acc[i][j], 0, 0, 0);
    __syncthreads();
  }

#pragma unroll
  for (int i = 0; i < 4; ++i) {
#pragma unroll
    for (int j = 0; j < 4; ++j) {
      int col = bn * 128 + wn + j * 16 + l16;
      int row0 = bm * 128 + wm + i * 16 + quad * 4;
#pragma unroll
      for (int r = 0; r < 4; ++r)
        C[(size_t)(row0 + r) * Ncols + col] = (bf16_t)acc[i][j][r];
    }
  }
}

// ---------------- layer-1 aggregation (bf16 gather), fused bias+relu+bf16 ------
__global__ void k_agg_l1(const bf16_t* __restrict__ H, const int* __restrict__ rs,
                         const int* __restrict__ csr, const float* __restrict__ dinv,
                         const float* __restrict__ b1, bf16_t* __restrict__ R,
                         int n, int mpad) {
  int d = blockIdx.x * 4 + (threadIdx.x >> 6);
  if (d >= mpad) return;
  int lane = threadIdx.x & 63;
  if (d >= n) {
    bf16x4 z;
    z[0] = (bf16_t)0.0f; z[1] = (bf16_t)0.0f; z[2] = (bf16_t)0.0f; z[3] = (bf16_t)0.0f;
    *(bf16x4*)(R + (size_t)d * HID + lane * 4) = z;
    return;
  }
  int e0 = rs[d], e1 = rs[d + 1];
  float a0 = 0.f, a1 = 0.f, a2 = 0.f, a3 = 0.f;
  float c0 = 0.f, c1 = 0.f, c2 = 0.f, c3 = 0.f;
  int e = e0;
  for (; e + 2 <= e1; e += 2) {
    int s0 = csr[e], s1 = csr[e + 1];
    float w0 = dinv[s0], w1 = dinv[s1];
    bf16x4 h0 = *(const bf16x4*)(H + (size_t)s0 * HID + lane * 4);
    bf16x4 h1 = *(const bf16x4*)(H + (size_t)s1 * HID + lane * 4);
    a0 += w0 * (float)h0[0]; a1 += w0 * (float)h0[1];
    a2 += w0 * (float)h0[2]; a3 += w0 * (float)h0[3];
    c0 += w1 * (float)h1[0]; c1 += w1 * (float)h1[1];
    c2 += w1 * (float)h1[2]; c3 += w1 * (float)h1[3];
  }
  if (e < e1) {
    int s0 = csr[e];
    float w0 = dinv[s0];
    bf16x4 h0 = *(const bf16x4*)(H + (size_t)s0 * HID + lane * 4);
    a0 += w0 * (float)h0[0]; a1 += w0 * (float)h0[1];
    a2 += w0 * (float)h0[2]; a3 += w0 * (float)h0[3];
  }
  a0 += c0; a1 += c1; a2 += c2; a3 += c3;
  float dd = dinv[d];
  float dv2 = dd * dd;
  bf16x4 hs = *(const bf16x4*)(H + (size_t)d * HID + lane * 4);
  float4 bb = ((const float4*)b1)[lane];
  float v0 = fmaxf(a0 * dd + dv2 * (float)hs[0] + bb.x, 0.f);
  float v1 = fmaxf(a1 * dd + dv2 * (float)hs[1] + bb.y, 0.f);
  float v2 = fmaxf(a2 * dd + dv2 * (float)hs[2] + bb.z, 0.f);
  float v3 = fmaxf(a3 * dd + dv2 * (float)hs[3] + bb.w, 0.f);
  bf16x4 o;
  o[0] = (bf16_t)v0; o[1] = (bf16_t)v1; o[2] = (bf16_t)v2; o[3] = (bf16_t)v3;
  *(bf16x4*)(R + (size_t)d * HID + lane * 4) = o;
}

// ---------------- layer-2 aggregation (bf16 gather), fused bias, fp32 out ------
__global__ void k_agg_l2(const bf16_t* __restrict__ H, const int* __restrict__ rs,
                         const int* __restrict__ csr, const float* __restrict__ dinv,
                         const float* __restrict__ b2, float* __restrict__ out, int n) {
  int d = blockIdx.x * 4 + (threadIdx.x >> 6);
  if (d >= n) return;
  int lane = threadIdx.x & 63;
  int e0 = rs[d], e1 = rs[d + 1];
  float a0 = 0.f, a1 = 0.f, c0 = 0.f, c1 = 0.f;
  int e = e0;
  for (; e + 2 <= e1; e += 2) {
    int s0 = csr[e], s1 = csr[e + 1];
    float w0 = dinv[s0], w1 = dinv[s1];
    bf16x2 h0 = *(const bf16x2*)(H + (size_t)s0 * OUTC + lane * 2);
    bf16x2 h1 = *(const bf16x2*)(H + (size_t)s1 * OUTC + lane * 2);
    a0 += w0 * (float)h0[0]; a1 += w0 * (float)h0[1];
    c0 += w1 * (float)h1[0]; c1 += w1 * (float)h1[1];
  }
  if (e < e1) {
    int s0 = csr[e];
    float w0 = dinv[s0];
    bf16x2 h0 = *(const bf16x2*)(H + (size_t)s0 * OUTC + lane * 2);
    a0 += w0 * (float)h0[0]; a1 += w0 * (float)h0[1];
  }
  a0 += c0; a1 += c1;
  float dd = dinv[d];
  float dv2 = dd * dd;
  bf16x2 hs = *(const bf16x2*)(H + (size_t)d * OUTC + lane * 2);
  float2 bb = ((const float2*)b2)[lane];
  float2 o;
  o.x = a0 * dd + dv2 * (float)hs[0] + bb.x;
  o.y = a1 * dd + dv2 * (float)hs[1] + bb.y;
  ((float2*)(out + (size_t)d * OUTC))[lane] = o;
}

// ---------------- launch ----------------
extern "C" void kernel_launch(void* const* d_in, const int* in_sizes, int n_in,
                              void* d_out, int out_size, void* d_ws, size_t ws_size,
                              hipStream_t stream) {
  const float* x  = (const float*)d_in[0];
  const void*  ei = d_in[1];
  const float* W1 = (const float*)d_in[2];
  const float* b1 = (const float*)d_in[3];
  const float* W2 = (const float*)d_in[4];
  const float* b2 = (const float*)d_in[5];

  const int n = in_sizes[0] / IN_C;   // 50000
  const int E = in_sizes[1] / 2;      // 800000
  const int mpad = (n + 127) & ~127;  // 50048

  char* w = (char*)d_ws;
  size_t off = 0;
  auto alloc = [&](size_t bytes) -> void* {
    void* p = w + off;
    off = (off + bytes + 255) & ~(size_t)255;
    return p;
  };

  int*    flag = (int*)alloc(4);
  int*    srcI = (int*)alloc((size_t)E * 4);
  int*    dstI = (int*)alloc((size_t)E * 4);
  int*    cnt  = (int*)alloc((size_t)n * 4);
  float*  dinv = (float*)alloc((size_t)n * 4);
  int*    rs   = (int*)alloc((size_t)(n + 1) * 4);
  int*    cur  = (int*)alloc((size_t)n * 4);
  int*    part = (int*)alloc(1024);
  int*    csr  = (int*)alloc((size_t)E * 4);
  bf16_t* Xb   = (bf16_t*)alloc((size_t)mpad * IN_C * 2);
  bf16_t* W1t  = (bf16_t*)alloc((size_t)HID * IN_C * 2);
  bf16_t* H1b  = (bf16_t*)alloc((size_t)mpad * HID * 2);
  bf16_t* R1b  = (bf16_t*)alloc((size_t)mpad * HID * 2);
  bf16_t* W2t  = (bf16_t*)alloc((size_t)OUTC * HID * 2);
  bf16_t* H2b  = (bf16_t*)alloc((size_t)mpad * OUTC * 2);
  (void)ws_size; (void)n_in; (void)out_size;

  const int nb = (n + 255) / 256;

  hipMemsetAsync(cnt, 0, (size_t)n * 4, stream);
  k_detect<<<1, 64, 0, stream>>>(ei, flag, n);
  k_decode_hist<<<(E + 255) / 256, 256, 0, stream>>>(ei, flag, srcI, dstI, cnt, E);
  k_dinv<<<nb, 256, 0, stream>>>(cnt, dinv, n);
  k_scan1<<<nb, 256, 0, stream>>>(cnt, rs, part, n);
  k_scan2<<<1, 256, 0, stream>>>(part, nb);
  k_scan3<<<nb, 256, 0, stream>>>(rs, part, cur, n, E);
  k_fill<<<(E + 255) / 256, 256, 0, stream>>>(srcI, dstI, cur, csr, E);

  k_convx<<<(mpad * 64 + 255) / 256, 256, 0, stream>>>(x, Xb, n, mpad);
  k_transpose<<<(IN_C * HID + 255) / 256, 256, 0, stream>>>(W1, W1t, IN_C, HID);
  k_transpose<<<(HID * OUTC + 255) / 256, 256, 0, stream>>>(W2, W2t, HID, OUTC);

  k_gemm<<<dim3(mpad / 128, HID / 128), 256, 0, stream>>>(Xb, W1t, H1b, IN_C, HID);
  k_agg_l1<<<(mpad + 3) / 4, 256, 0, stream>>>(H1b, rs, csr, dinv, b1, R1b, n, mpad);
  k_gemm<<<dim3(mpad / 128, OUTC / 128), 256, 0, stream>>>(R1b, W2t, H2b, HID, OUTC);
  k_agg_l2<<<(n + 3) / 4, 256, 0, stream>>>(H2b, rs, csr, dinv, b2, (float*)d_out, n);
}

// Round 3
// 401.308 us; speedup vs baseline: 1.2905x; 1.0509x over previous
//
#include <hip/hip_runtime.h>
#include <stdint.h>

typedef __bf16 bf16_t;
typedef bf16_t bf16x8 __attribute__((ext_vector_type(8)));
typedef bf16_t bf16x4 __attribute__((ext_vector_type(4)));
typedef bf16_t bf16x2 __attribute__((ext_vector_type(2)));
typedef float  f32x4  __attribute__((ext_vector_type(4)));

#define IN_C 512
#define HID  256
#define OUTC 128

// ---------------- edge format detection ----------------
__global__ void k_detect(const void* __restrict__ ei, int* __restrict__ flag, int n_nodes) {
  if (blockIdx.x == 0 && threadIdx.x == 0) {
    const long long* p = (const long long*)ei;
    int ok = 1;
    for (int i = 0; i < 64; ++i) {
      long long v = p[i];
      if (v < 0 || v >= n_nodes) ok = 0;
    }
    *flag = ok;  // 1 => int64 layout, 0 => int32 layout
  }
}

// degree histogram straight from edge_index
__global__ void k_hist(const void* __restrict__ ei, const int* __restrict__ flag,
                       int* __restrict__ cnt, int E) {
  int e = blockIdx.x * blockDim.x + threadIdx.x;
  if (e >= E) return;
  int d;
  if (*flag) d = (int)((const long long*)ei)[(size_t)E + e];
  else       d = ((const int*)ei)[E + e];
  atomicAdd(&cnt[d], 1);
}

// ---------------- CSR build: scan (3 kernels, dinv fused) + fill ----------------
__global__ void k_scan1(const int* __restrict__ cnt, int* __restrict__ ex,
                        int* __restrict__ part, float* __restrict__ dinv, int n) {
  __shared__ int sh[256];
  int i = blockIdx.x * 256 + threadIdx.x;
  int v = (i < n) ? cnt[i] : 0;
  if (i < n) dinv[i] = rsqrtf((float)v + 1.0f);  // +1 self-loop
  sh[threadIdx.x] = v;
  __syncthreads();
  int val = v;
  for (int off = 1; off < 256; off <<= 1) {
    int t = (threadIdx.x >= off) ? sh[threadIdx.x - off] : 0;
    __syncthreads();
    val += t;
    sh[threadIdx.x] = val;
    __syncthreads();
  }
  if (i < n) ex[i] = val - v;
  if (threadIdx.x == 255) part[blockIdx.x] = val;
}

__global__ void k_scan2(int* __restrict__ part, int nb) {
  __shared__ int sh[256];
  int v = (threadIdx.x < nb) ? part[threadIdx.x] : 0;
  sh[threadIdx.x] = v;
  __syncthreads();
  int val = v;
  for (int off = 1; off < 256; off <<= 1) {
    int t = (threadIdx.x >= off) ? sh[threadIdx.x - off] : 0;
    __syncthreads();
    val += t;
    sh[threadIdx.x] = val;
    __syncthreads();
  }
  if (threadIdx.x < nb) part[threadIdx.x] = val - v;
}

__global__ void k_scan3(int* __restrict__ rs, const int* __restrict__ part,
                        int* __restrict__ cur, int n, int Etot) {
  int i = blockIdx.x * 256 + threadIdx.x;
  if (i < n) {
    int r = rs[i] + part[blockIdx.x];
    rs[i] = r;
    cur[i] = r;
  }
  if (i == 0) rs[n] = Etot;
}

// CSR fill straight from edge_index
__global__ void k_fill(const void* __restrict__ ei, const int* __restrict__ flag,
                       int* __restrict__ cur, int* __restrict__ csr, int E) {
  int e = blockIdx.x * blockDim.x + threadIdx.x;
  if (e >= E) return;
  int s, d;
  if (*flag) {
    const long long* p = (const long long*)ei;
    s = (int)p[e];
    d = (int)p[(size_t)E + e];
  } else {
    const int* p = (const int*)ei;
    s = p[e];
    d = p[E + e];
  }
  int pos = atomicAdd(&cur[d], 1);
  csr[pos] = s;
}

// ---------------- weight transposes (both in one kernel) ----------------
// W1 [512,256] -> W1t [256,512] bf16 ; W2 [256,128] -> W2t [128,256] bf16
__global__ void k_transw(const float* __restrict__ W1, const float* __restrict__ W2,
                         bf16_t* __restrict__ W1t, bf16_t* __restrict__ W2t) {
  int t = blockIdx.x * blockDim.x + threadIdx.x;
  if (t < IN_C * HID) {
    int k = t / HID, nn = t % HID;
    W1t[(size_t)nn * IN_C + k] = (bf16_t)W1[t];
  } else {
    int u = t - IN_C * HID;
    if (u < HID * OUTC) {
      int k = u / OUTC, nn = u % OUTC;
      W2t[(size_t)nn * HID + k] = (bf16_t)W2[u];
    }
  }
}

// ---------------- GEMM1: H1b[mpad,256] = bf16( x[fp32][n,512] @ W1 ) ----------
// BM=64, BN=256(full), BK=32. 256 threads = 4 waves (2x2), wave tile 32x128.
__global__ __launch_bounds__(256, 2) void k_gemm1(const float* __restrict__ x,
                                                  const bf16_t* __restrict__ Bt,
                                                  bf16_t* __restrict__ C, int n) {
  __shared__ bf16_t As[64 * 40];
  __shared__ bf16_t Bs[256 * 40];
  const int bm = blockIdx.x;
  const int tid = threadIdx.x;
  const int wave = tid >> 6, lane = tid & 63;
  const int wm = (wave >> 1) * 32, wn = (wave & 1) * 128;
  const int quad = lane >> 4, l16 = lane & 15;
  const int arow = tid >> 2, acol = (tid & 3) * 8;  // A stage: 8 fp32 each
  const int grow = bm * 64 + arow;

  f32x4 acc[2][8];
  for (int i = 0; i < 2; ++i)
    for (int j = 0; j < 8; ++j)
      for (int r = 0; r < 4; ++r) acc[i][j][r] = 0.0f;

  for (int kk = 0; kk < IN_C; kk += 32) {
    // stage A (fp32 -> bf16)
    bf16x8 va;
    if (grow < n) {
      const float4* px = (const float4*)(x + (size_t)grow * IN_C + kk + acol);
      float4 a = px[0], b = px[1];
      va[0] = (bf16_t)a.x; va[1] = (bf16_t)a.y; va[2] = (bf16_t)a.z; va[3] = (bf16_t)a.w;
      va[4] = (bf16_t)b.x; va[5] = (bf16_t)b.y; va[6] = (bf16_t)b.z; va[7] = (bf16_t)b.w;
    } else {
      for (int i = 0; i < 8; ++i) va[i] = (bf16_t)0.0f;
    }
    *(bf16x8*)(&As[arow * 40 + acol]) = va;
    // stage B: row = tid, cols kk..kk+31
#pragma unroll
    for (int c = 0; c < 4; ++c) {
      bf16x8 vb = *(const bf16x8*)(Bt + (size_t)tid * IN_C + kk + c * 8);
      *(bf16x8*)(&Bs[tid * 40 + c * 8]) = vb;
    }
    __syncthreads();
    bf16x8 af[2], bfr[8];
#pragma unroll
    for (int i = 0; i < 2; ++i)
      af[i] = *(const bf16x8*)(&As[(wm + i * 16 + l16) * 40 + quad * 8]);
#pragma unroll
    for (int j = 0; j < 8; ++j)
      bfr[j] = *(const bf16x8*)(&Bs[(wn + j * 16 + l16) * 40 + quad * 8]);
#pragma unroll
    for (int i = 0; i < 2; ++i)
#pragma unroll
      for (int j = 0; j < 8; ++j)
        acc[i][j] = __builtin_amdgcn_mfma_f32_16x16x32_bf16(af[i], bfr[j], acc[i][j], 0, 0, 0);
    __syncthreads();
  }

#pragma unroll
  for (int i = 0; i < 2; ++i) {
#pragma unroll
    for (int j = 0; j < 8; ++j) {
      int col = wn + j * 16 + l16;
      int row0 = bm * 64 + wm + i * 16 + quad * 4;
#pragma unroll
      for (int r = 0; r < 4; ++r)
        C[(size_t)(row0 + r) * HID + col] = (bf16_t)acc[i][j][r];
    }
  }
}

// ---------------- GEMM2: H2b[mpad,128] = bf16( R1b[mpad,256] @ W2 ) ----------
// BM=64, BN=128(full), BK=32. 256 threads = 4 waves (2x2), wave tile 32x64.
__global__ __launch_bounds__(256, 2) void k_gemm2(const bf16_t* __restrict__ A,
                                                  const bf16_t* __restrict__ Bt,
                                                  bf16_t* __restrict__ C) {
  __shared__ bf16_t As[64 * 40];
  __shared__ bf16_t Bs[128 * 40];
  const int bm = blockIdx.x;
  const int tid = threadIdx.x;
  const int wave = tid >> 6, lane = tid & 63;
  const int wm = (wave >> 1) * 32, wn = (wave & 1) * 64;
  const int quad = lane >> 4, l16 = lane & 15;
  const int arow = tid >> 2, acol = (tid & 3) * 8;
  const int brow = tid >> 1, bcol = (tid & 1) * 16;

  f32x4 acc[2][4];
  for (int i = 0; i < 2; ++i)
    for (int j = 0; j < 4; ++j)
      for (int r = 0; r < 4; ++r) acc[i][j][r] = 0.0f;

  for (int kk = 0; kk < HID; kk += 32) {
    bf16x8 va = *(const bf16x8*)(A + (size_t)(bm * 64 + arow) * HID + kk + acol);
    *(bf16x8*)(&As[arow * 40 + acol]) = va;
#pragma unroll
    for (int c = 0; c < 2; ++c) {
      bf16x8 vb = *(const bf16x8*)(Bt + (size_t)brow * HID + kk + bcol + c * 8);
      *(bf16x8*)(&Bs[brow * 40 + bcol + c * 8]) = vb;
    }
    __syncthreads();
    bf16x8 af[2], bfr[4];
#pragma unroll
    for (int i = 0; i < 2; ++i)
      af[i] = *(const bf16x8*)(&As[(wm + i * 16 + l16) * 40 + quad * 8]);
#pragma unroll
    for (int j = 0; j < 4; ++j)
      bfr[j] = *(const bf16x8*)(&Bs[(wn + j * 16 + l16) * 40 + quad * 8]);
#pragma unroll
    for (int i = 0; i < 2; ++i)
#pragma unroll
      for (int j = 0; j < 4; ++j)
        acc[i][j] = __builtin_amdgcn_mfma_f32_16x16x32_bf16(af[i], bfr[j], acc[i][j], 0, 0, 0);
    __syncthreads();
  }

#pragma unroll
  for (int i = 0; i < 2; ++i) {
#pragma unroll
    for (int j = 0; j < 4; ++j) {
      int col = wn + j * 16 + l16;
      int row0 = bm * 64 + wm + i * 16 + quad * 4;
#pragma unroll
      for (int r = 0; r < 4; ++r)
        C[(size_t)(row0 + r) * OUTC + col] = (bf16_t)acc[i][j][r];
    }
  }
}

// ---------------- layer-1 aggregation (bf16 gather, 4-way unrolled) ----------
__global__ void k_agg_l1(const bf16_t* __restrict__ H, const int* __restrict__ rs,
                         const int* __restrict__ csr, const float* __restrict__ dinv,
                         const float* __restrict__ b1, bf16_t* __restrict__ R,
                         int n, int mpad) {
  int d = blockIdx.x * 4 + (threadIdx.x >> 6);
  if (d >= mpad) return;
  int lane = threadIdx.x & 63;
  if (d >= n) {
    bf16x4 z;
    z[0] = (bf16_t)0.0f; z[1] = (bf16_t)0.0f; z[2] = (bf16_t)0.0f; z[3] = (bf16_t)0.0f;
    *(bf16x4*)(R + (size_t)d * HID + lane * 4) = z;
    return;
  }
  int e0 = rs[d], e1 = rs[d + 1];
  float acc[4][4];
  for (int k = 0; k < 4; ++k)
    for (int c = 0; c < 4; ++c) acc[k][c] = 0.f;
  int e = e0;
  for (; e + 4 <= e1; e += 4) {
    int s0 = csr[e], s1 = csr[e + 1], s2 = csr[e + 2], s3 = csr[e + 3];
    float w0 = dinv[s0], w1 = dinv[s1], w2 = dinv[s2], w3 = dinv[s3];
    bf16x4 h0 = *(const bf16x4*)(H + (size_t)s0 * HID + lane * 4);
    bf16x4 h1 = *(const bf16x4*)(H + (size_t)s1 * HID + lane * 4);
    bf16x4 h2 = *(const bf16x4*)(H + (size_t)s2 * HID + lane * 4);
    bf16x4 h3 = *(const bf16x4*)(H + (size_t)s3 * HID + lane * 4);
#pragma unroll
    for (int c = 0; c < 4; ++c) {
      acc[0][c] += w0 * (float)h0[c];
      acc[1][c] += w1 * (float)h1[c];
      acc[2][c] += w2 * (float)h2[c];
      acc[3][c] += w3 * (float)h3[c];
    }
  }
  for (; e < e1; ++e) {
    int s0 = csr[e];
    float w0 = dinv[s0];
    bf16x4 h0 = *(const bf16x4*)(H + (size_t)s0 * HID + lane * 4);
#pragma unroll
    for (int c = 0; c < 4; ++c) acc[0][c] += w0 * (float)h0[c];
  }
  float dd = dinv[d];
  float dv2 = dd * dd;
  bf16x4 hs = *(const bf16x4*)(H + (size_t)d * HID + lane * 4);
  float4 bb = ((const float4*)b1)[lane];
  float a0 = acc[0][0] + acc[1][0] + acc[2][0] + acc[3][0];
  float a1 = acc[0][1] + acc[1][1] + acc[2][1] + acc[3][1];
  float a2 = acc[0][2] + acc[1][2] + acc[2][2] + acc[3][2];
  float a3 = acc[0][3] + acc[1][3] + acc[2][3] + acc[3][3];
  float v0 = fmaxf(a0 * dd + dv2 * (float)hs[0] + bb.x, 0.f);
  float v1 = fmaxf(a1 * dd + dv2 * (float)hs[1] + bb.y, 0.f);
  float v2 = fmaxf(a2 * dd + dv2 * (float)hs[2] + bb.z, 0.f);
  float v3 = fmaxf(a3 * dd + dv2 * (float)hs[3] + bb.w, 0.f);
  bf16x4 o;
  o[0] = (bf16_t)v0; o[1] = (bf16_t)v1; o[2] = (bf16_t)v2; o[3] = (bf16_t)v3;
  *(bf16x4*)(R + (size_t)d * HID + lane * 4) = o;
}

// ---------------- layer-2 aggregation (bf16 gather, 4-way unrolled) ----------
__global__ void k_agg_l2(const bf16_t* __restrict__ H, const int* __restrict__ rs,
                         const int* __restrict__ csr, const float* __restrict__ dinv,
                         const float* __restrict__ b2, float* __restrict__ out, int n) {
  int d = blockIdx.x * 4 + (threadIdx.x >> 6);
  if (d >= n) return;
  int lane = threadIdx.x & 63;
  int e0 = rs[d], e1 = rs[d + 1];
  float acc[4][2];
  for (int k = 0; k < 4; ++k) { acc[k][0] = 0.f; acc[k][1] = 0.f; }
  int e = e0;
  for (; e + 4 <= e1; e += 4) {
    int s0 = csr[e], s1 = csr[e + 1], s2 = csr[e + 2], s3 = csr[e + 3];
    float w0 = dinv[s0], w1 = dinv[s1], w2 = dinv[s2], w3 = dinv[s3];
    bf16x2 h0 = *(const bf16x2*)(H + (size_t)s0 * OUTC + lane * 2);
    bf16x2 h1 = *(const bf16x2*)(H + (size_t)s1 * OUTC + lane * 2);
    bf16x2 h2 = *(const bf16x2*)(H + (size_t)s2 * OUTC + lane * 2);
    bf16x2 h3 = *(const bf16x2*)(H + (size_t)s3 * OUTC + lane * 2);
    acc[0][0] += w0 * (float)h0[0]; acc[0][1] += w0 * (float)h0[1];
    acc[1][0] += w1 * (float)h1[0]; acc[1][1] += w1 * (float)h1[1];
    acc[2][0] += w2 * (float)h2[0]; acc[2][1] += w2 * (float)h2[1];
    acc[3][0] += w3 * (float)h3[0]; acc[3][1] += w3 * (float)h3[1];
  }
  for (; e < e1; ++e) {
    int s0 = csr[e];
    float w0 = dinv[s0];
    bf16x2 h0 = *(const bf16x2*)(H + (size_t)s0 * OUTC + lane * 2);
    acc[0][0] += w0 * (float)h0[0]; acc[0][1] += w0 * (float)h0[1];
  }
  float a0 = acc[0][0] + acc[1][0] + acc[2][0] + acc[3][0];
  float a1 = acc[0][1] + acc[1][1] + acc[2][1] + acc[3][1];
  float dd = dinv[d];
  float dv2 = dd * dd;
  bf16x2 hs = *(const bf16x2*)(H + (size_t)d * OUTC + lane * 2);
  float2 bb = ((const float2*)b2)[lane];
  float2 o;
  o.x = a0 * dd + dv2 * (float)hs[0] + bb.x;
  o.y = a1 * dd + dv2 * (float)hs[1] + bb.y;
  ((float2*)(out + (size_t)d * OUTC))[lane] = o;
}

// ---------------- launch ----------------
extern "C" void kernel_launch(void* const* d_in, const int* in_sizes, int n_in,
                              void* d_out, int out_size, void* d_ws, size_t ws_size,
                              hipStream_t stream) {
  const float* x  = (const float*)d_in[0];
  const void*  ei = d_in[1];
  const float* W1 = (const float*)d_in[2];
  const float* b1 = (const float*)d_in[3];
  const float* W2 = (const float*)d_in[4];
  const float* b2 = (const float*)d_in[5];

  const int n = in_sizes[0] / IN_C;   // 50000
  const int E = in_sizes[1] / 2;      // 800000
  const int mpad = (n + 63) & ~63;    // 50048 (multiple of 64)

  char* w = (char*)d_ws;
  size_t off = 0;
  auto alloc = [&](size_t bytes) -> void* {
    void* p = w + off;
    off = (off + bytes + 255) & ~(size_t)255;
    return p;
  };

  int*    flag = (int*)alloc(4);
  int*    cnt  = (int*)alloc((size_t)n * 4);
  float*  dinv = (float*)alloc((size_t)n * 4);
  int*    rs   = (int*)alloc((size_t)(n + 1) * 4);
  int*    cur  = (int*)alloc((size_t)n * 4);
  int*    part = (int*)alloc(1024);
  int*    csr  = (int*)alloc((size_t)E * 4);
  bf16_t* W1t  = (bf16_t*)alloc((size_t)HID * IN_C * 2);
  bf16_t* W2t  = (bf16_t*)alloc((size_t)OUTC * HID * 2);
  bf16_t* H1b  = (bf16_t*)alloc((size_t)mpad * HID * 2);
  bf16_t* R1b  = (bf16_t*)alloc((size_t)mpad * HID * 2);
  bf16_t* H2b  = (bf16_t*)alloc((size_t)mpad * OUTC * 2);
  (void)ws_size; (void)n_in; (void)out_size;

  const int nb = (n + 255) / 256;

  hipMemsetAsync(cnt, 0, (size_t)n * 4, stream);
  k_detect<<<1, 64, 0, stream>>>(ei, flag, n);
  k_hist<<<(E + 255) / 256, 256, 0, stream>>>(ei, flag, cnt, E);
  k_scan1<<<nb, 256, 0, stream>>>(cnt, rs, part, dinv, n);
  k_scan2<<<1, 256, 0, stream>>>(part, nb);
  k_scan3<<<nb, 256, 0, stream>>>(rs, part, cur, n, E);
  k_fill<<<(E + 255) / 256, 256, 0, stream>>>(ei, flag, cur, csr, E);
  k_transw<<<(IN_C * HID + HID * OUTC + 255) / 256, 256, 0, stream>>>(W1, W2, W1t, W2t);

  k_gemm1<<<mpad / 64, 256, 0, stream>>>(x, W1t, H1b, n);
  k_agg_l1<<<(mpad + 3) / 4, 256, 0, stream>>>(H1b, rs, csr, dinv, b1, R1b, n, mpad);
  k_gemm2<<<mpad / 64, 256, 0, stream>>>(R1b, W2t, H2b);
  k_agg_l2<<<(n + 3) / 4, 256, 0, stream>>>(H2b, rs, csr, dinv, b2, (float*)d_out, n);
}